// Round 1
// baseline (4469.669 us; speedup 1.0000x reference)
//
#include <hip/hip_runtime.h>

typedef unsigned short ushort_t;
typedef __attribute__((ext_vector_type(8))) short short8;
typedef __attribute__((ext_vector_type(4))) float float4v;

#define HW 16384
#define A_BINS 180
#define R_BINS 182
#define AP 188              // A padded by 4 each side
#define CCH 64
#define NB 4
#define MROWS (A_BINS * R_BINS)      // 32760 output rows per batch
#define MPROWS (AP * R_BINS)         // 34216 padded rows per batch

static __device__ __forceinline__ float b2f(ushort_t u) {
    union { unsigned u32; float f; } c; c.u32 = ((unsigned)u) << 16; return c.f;
}
static __device__ __forceinline__ ushort_t f2b(float f) {
    union { float f; unsigned u; } c; c.f = f;
    unsigned r = c.u + 0x7fffu + ((c.u >> 16) & 1u);   // RNE
    return (ushort_t)(r >> 16);
}

// ---------------- transpose x [256][16384] f32 -> xT [16384][256] bf16 ----------------
__global__ __launch_bounds__(256) void k_transpose(const float* __restrict__ x,
                                                   ushort_t* __restrict__ xT) {
    __shared__ float tile[64][65];
    int t = threadIdx.x, lane = t & 63, g = t >> 6;
    int pBase = blockIdx.x * 64;     // pixel tile
    int ncBase = blockIdx.y * 64;    // channel tile
#pragma unroll
    for (int i = 0; i < 16; ++i) {
        int ncl = g + i * 4;
        tile[ncl][lane] = x[(size_t)(ncBase + ncl) * HW + pBase + lane];
    }
    __syncthreads();
#pragma unroll
    for (int i = 0; i < 16; ++i) {
        int pl = g + i * 4;
        xT[(size_t)(pBase + pl) * 256 + ncBase + lane] = f2b(tile[lane][pl]);
    }
}

// ---------------- zero the A-padding rows of the three padded buffers ----------------
__global__ __launch_bounds__(256) void k_zero_pads(ushort_t* __restrict__ ht0,
                                                   ushort_t* __restrict__ bufA,
                                                   ushort_t* __restrict__ bufB) {
    int b = blockIdx.x >> 5;           // 0..2 buffer
    int idx = blockIdx.x & 31;         // n*8 + j
    int n = idx >> 3, j = idx & 7;
    int ap = (j < 4) ? j : (184 + (j - 4));
    ushort_t* base = (b == 0 ? ht0 : (b == 1 ? bufA : bufB));
    base += (size_t)(n * AP + ap) * (R_BINS * CCH);
    for (int i = threadIdx.x; i < R_BINS * CCH; i += 256) base[i] = 0;
}

// ---------------- repack conv weights (64,64,9) f32 -> MFMA B-fragment bf16 ----------------
// layout: [(k*2+h)*4 + cot][lane][j]  with B[kk=(lane>>4)*8+j][nn=lane&15]
__global__ __launch_bounds__(256) void k_repack(const float* __restrict__ w2,
                                                const float* __restrict__ w3,
                                                ushort_t* __restrict__ w2b,
                                                ushort_t* __restrict__ w3b) {
    const float* w = blockIdx.y ? w3 : w2;
    ushort_t* wb = blockIdx.y ? w3b : w2b;
    int idx = blockIdx.x * 256 + threadIdx.x;   // 0..36863
    int j = idx & 7;
    int lane = (idx >> 3) & 63;
    int cot = (idx >> 9) & 3;
    int h = (idx >> 11) & 1;
    int k = idx >> 12;
    int co = cot * 16 + (lane & 15);
    int ci = h * 32 + (lane >> 4) * 8 + j;
    wb[idx] = f2b(w[(co * 64 + ci) * 9 + k]);
}

// ---------------- DHT: scatter x into hough space, LDS fp32 accumulators ----------------
__global__ __launch_bounds__(256) void k_dht(const ushort_t* __restrict__ xT,
                                             const int* __restrict__ rho,
                                             ushort_t* __restrict__ ht0) {
    __shared__ float acc[R_BINS * CCH];   // 46.6 KB
    int a = blockIdx.x, n = blockIdx.y;
    int t = threadIdx.x, lane = t & 63, wv = t >> 6;
    for (int i = t; i < R_BINS * CCH; i += 256) acc[i] = 0.f;
    __syncthreads();
    const int* rhoA = rho + (size_t)a * HW;
    const ushort_t* xn = xT + n * 64;
    int base = wv * 4096;
    for (int c = 0; c < 64; ++c) {
        int pb = base + c * 64;
        int rv = rhoA[pb + lane];           // 64 rho values, one per lane
#pragma unroll 8
        for (int i = 0; i < 64; ++i) {
            int r = __shfl(rv, i);
            float v = b2f(xn[(size_t)(pb + i) * 256 + lane]);
            atomicAdd(&acc[r * CCH + lane], v);
        }
    }
    __syncthreads();
    size_t ob = (size_t)(n * AP + a + 4) * (R_BINS * CCH);
    for (int i = t; i < R_BINS * CCH; i += 256) ht0[ob + i] = f2b(acc[i]);
}

// ---------------- depthwise (9,1) conv + bias + relu ----------------
__global__ __launch_bounds__(256) void k_conv1(const ushort_t* __restrict__ ht0,
                                               const float* __restrict__ w1,
                                               const float* __restrict__ b1,
                                               ushort_t* __restrict__ bufA) {
    int t = threadIdx.x, c = t & 63, rr = t >> 6;
    int r = blockIdx.x * 4 + rr;
    int a = blockIdx.y, n = blockIdx.z;
    if (r >= R_BINS) return;
    float acc = b1[c];
    size_t base = ((size_t)(n * AP + a) * R_BINS + r) * CCH + c;
#pragma unroll
    for (int k = 0; k < 9; ++k)
        acc += b2f(ht0[base + (size_t)k * (R_BINS * CCH)]) * w1[c * 9 + k];
    acc = fmaxf(acc, 0.f);
    bufA[((size_t)(n * AP + a + 4) * R_BINS + r) * CCH + c] = f2b(acc);
}

// ---------------- dense (9,1) conv as MFMA GEMM: M=32760, N=64, K=576 ----------------
__global__ __launch_bounds__(256) void k_gemm(const ushort_t* __restrict__ in,
                                              const ushort_t* __restrict__ wb,
                                              const float* __restrict__ bias,
                                              ushort_t* __restrict__ out,
                                              int outOff, int outStrideN) {
    int t = threadIdx.x, lane = t & 63, wv = t >> 6;
    int m = lane & 15, q = lane >> 4;
    int n = blockIdx.y;
    int rowBase = blockIdx.x * 64 + wv * 16;
    int row = rowBase + m;
    int rowc = row < MROWS ? row : (MROWS - 1);
    const ushort_t* inN = in + (size_t)n * MPROWS * CCH;
    float4v acc[4];
#pragma unroll
    for (int i = 0; i < 4; ++i) acc[i] = (float4v){0.f, 0.f, 0.f, 0.f};

#pragma unroll
    for (int k = 0; k < 9; ++k) {
#pragma unroll
        for (int h = 0; h < 2; ++h) {
            short8 af = *(const short8*)(inN + (size_t)(rowc + k * R_BINS) * CCH + h * 32 + q * 8);
            const ushort_t* wbb = wb + (size_t)((k * 2 + h) * 4) * 512 + lane * 8;
            short8 b0 = *(const short8*)(wbb);
            short8 b1v = *(const short8*)(wbb + 512);
            short8 b2v = *(const short8*)(wbb + 1024);
            short8 b3v = *(const short8*)(wbb + 1536);
            acc[0] = __builtin_amdgcn_mfma_f32_16x16x32_bf16(af, b0, acc[0], 0, 0, 0);
            acc[1] = __builtin_amdgcn_mfma_f32_16x16x32_bf16(af, b1v, acc[1], 0, 0, 0);
            acc[2] = __builtin_amdgcn_mfma_f32_16x16x32_bf16(af, b2v, acc[2], 0, 0, 0);
            acc[3] = __builtin_amdgcn_mfma_f32_16x16x32_bf16(af, b3v, acc[3], 0, 0, 0);
        }
    }

    ushort_t* outN = out + (size_t)n * outStrideN + outOff;
#pragma unroll
    for (int cot = 0; cot < 4; ++cot) {
        int co = cot * 16 + m;
        float bv = bias[co];
#pragma unroll
        for (int i = 0; i < 4; ++i) {
            int rowD = rowBase + q * 4 + i;
            float v = fmaxf(acc[cot][i] + bv, 0.f);
            if (rowD < MROWS) outN[(size_t)rowD * CCH + co] = f2b(v);
        }
    }
}

// ---------------- inverse DHT: gather + LDS transpose for coalesced f32 stores ----------------
__global__ __launch_bounds__(256) void k_idht(const ushort_t* __restrict__ buf3,
                                              const int* __restrict__ rho,
                                              float* __restrict__ outp) {
    __shared__ float tile[64][65];
    int t = threadIdx.x, lane = t & 63, wv = t >> 6;
    int n = blockIdx.y;
    int P0 = blockIdx.x * 64;
    int pw = P0 + wv * 16;
    float acc[16];
#pragma unroll
    for (int i = 0; i < 16; ++i) acc[i] = 0.f;
    const ushort_t* bn = buf3 + (size_t)n * A_BINS * R_BINS * CCH;
    for (int a = 0; a < A_BINS; ++a) {
        int rv = (lane < 16) ? rho[(size_t)a * HW + pw + lane] : 0;
        const ushort_t* ba = bn + (size_t)a * R_BINS * CCH;
#pragma unroll
        for (int i = 0; i < 16; ++i) {
            int r = __shfl(rv, i);
            acc[i] += b2f(ba[r * CCH + lane]);
        }
    }
#pragma unroll
    for (int i = 0; i < 16; ++i) tile[wv * 16 + i][lane] = acc[i];
    __syncthreads();
    float* on = outp + (size_t)n * CCH * HW;
#pragma unroll
    for (int i = 0; i < 16; ++i) {
        int c = wv + i * 4;
        on[(size_t)c * HW + P0 + lane] = tile[lane][c];
    }
}

extern "C" void kernel_launch(void* const* d_in, const int* in_sizes, int n_in,
                              void* d_out, int out_size, void* d_ws, size_t ws_size,
                              hipStream_t stream) {
    const float* x   = (const float*)d_in[0];
    const int*   rho = (const int*)d_in[1];
    const float* w1  = (const float*)d_in[2];
    const float* b1  = (const float*)d_in[3];
    const float* w2  = (const float*)d_in[4];
    const float* b2  = (const float*)d_in[5];
    const float* w3  = (const float*)d_in[6];
    const float* b3  = (const float*)d_in[7];
    float* outp = (float*)d_out;

    char* ws = (char*)d_ws;
    size_t off = 0;
    auto alloc = [&](size_t bytes) -> void* {
        void* p = ws + off;
        off = (off + bytes + 255) & ~(size_t)255;
        return p;
    };
    ushort_t* xT   = (ushort_t*)alloc((size_t)HW * 256 * 2);            // 8 MB
    ushort_t* ht0  = (ushort_t*)alloc((size_t)NB * MPROWS * CCH * 2);   // 17.5 MB
    ushort_t* bufA = (ushort_t*)alloc((size_t)NB * MPROWS * CCH * 2);   // 17.5 MB
    ushort_t* bufB = (ushort_t*)alloc((size_t)NB * MPROWS * CCH * 2);   // 17.5 MB
    ushort_t* buf3 = (ushort_t*)alloc((size_t)NB * MROWS * CCH * 2);    // 16.8 MB
    ushort_t* w2b  = (ushort_t*)alloc(36864 * 2);
    ushort_t* w3b  = (ushort_t*)alloc(36864 * 2);

    k_transpose<<<dim3(256, 4), 256, 0, stream>>>(x, xT);
    k_zero_pads<<<96, 256, 0, stream>>>(ht0, bufA, bufB);
    k_repack<<<dim3(144, 2), 256, 0, stream>>>(w2, w3, w2b, w3b);
    k_dht<<<dim3(A_BINS, NB), 256, 0, stream>>>(xT, rho, ht0);
    k_conv1<<<dim3(46, A_BINS, NB), 256, 0, stream>>>(ht0, w1, b1, bufA);
    k_gemm<<<dim3(512, NB), 256, 0, stream>>>(bufA, w2b, b2, bufB, 728 * CCH, MPROWS * CCH);
    k_gemm<<<dim3(512, NB), 256, 0, stream>>>(bufB, w3b, b3, buf3, 0, MROWS * CCH);
    k_idht<<<dim3(256, NB), 256, 0, stream>>>(buf3, rho, outp);
}

// Round 2
// 630.596 us; speedup vs baseline: 7.0880x; 7.0880x over previous
//
#include <hip/hip_runtime.h>

typedef unsigned short ushort_t;
typedef __attribute__((ext_vector_type(8))) short short8;
typedef __attribute__((ext_vector_type(4))) float float4v;

#define HW 16384
#define A_BINS 180
#define R_BINS 182
#define AP 188              // A padded by 4 each side
#define CCH 64
#define NB 4
#define MROWS (A_BINS * R_BINS)      // 32760 output rows per batch
#define MPROWS (AP * R_BINS)         // 34216 padded rows per batch

static __device__ __forceinline__ float b2f(ushort_t u) {
    union { unsigned u32; float f; } c; c.u32 = ((unsigned)u) << 16; return c.f;
}
static __device__ __forceinline__ ushort_t f2b(float f) {
    union { float f; unsigned u; } c; c.f = f;
    unsigned r = c.u + 0x7fffu + ((c.u >> 16) & 1u);   // RNE
    return (ushort_t)(r >> 16);
}

// ---------------- transpose x [256][16384] f32 -> xT [16384][256] bf16 ----------------
__global__ __launch_bounds__(256) void k_transpose(const float* __restrict__ x,
                                                   ushort_t* __restrict__ xT) {
    __shared__ float tile[64][65];
    int t = threadIdx.x, lane = t & 63, g = t >> 6;
    int pBase = blockIdx.x * 64;     // pixel tile
    int ncBase = blockIdx.y * 64;    // channel tile
#pragma unroll
    for (int i = 0; i < 16; ++i) {
        int ncl = g + i * 4;
        tile[ncl][lane] = x[(size_t)(ncBase + ncl) * HW + pBase + lane];
    }
    __syncthreads();
#pragma unroll
    for (int i = 0; i < 16; ++i) {
        int pl = g + i * 4;
        xT[(size_t)(pBase + pl) * 256 + ncBase + lane] = f2b(tile[lane][pl]);
    }
}

// ---------------- zero the A-padding rows of the padded buffers ----------------
__global__ __launch_bounds__(256) void k_zero_pads(ushort_t* __restrict__ ht0,
                                                   ushort_t* __restrict__ bufA,
                                                   ushort_t* __restrict__ bufB) {
    int b = blockIdx.x >> 5;           // 0..2 buffer
    int idx = blockIdx.x & 31;         // n*8 + j
    int n = idx >> 3, j = idx & 7;
    int ap = (j < 4) ? j : (184 + (j - 4));
    ushort_t* base = (b == 0 ? ht0 : (b == 1 ? bufA : bufB));
    base += (size_t)(n * AP + ap) * (R_BINS * CCH);
    for (int i = threadIdx.x; i < R_BINS * CCH; i += 256) base[i] = 0;
}

// ---------------- repack conv weights (64,64,9) f32 -> MFMA B-fragment bf16 ----------------
__global__ __launch_bounds__(256) void k_repack(const float* __restrict__ w2,
                                                const float* __restrict__ w3,
                                                ushort_t* __restrict__ w2b,
                                                ushort_t* __restrict__ w3b) {
    const float* w = blockIdx.y ? w3 : w2;
    ushort_t* wb = blockIdx.y ? w3b : w2b;
    int idx = blockIdx.x * 256 + threadIdx.x;   // 0..36863
    int j = idx & 7;
    int lane = (idx >> 3) & 63;
    int cot = (idx >> 9) & 3;
    int h = (idx >> 11) & 1;
    int k = idx >> 12;
    int co = cot * 16 + (lane & 15);
    int ci = h * 32 + (lane >> 4) * 8 + j;
    wb[idx] = f2b(w[(co * 64 + ci) * 9 + k]);
}

// ---------------- build per-angle CSR: bin -> pixel list (atomic-free hot path later) ----------
__global__ __launch_bounds__(256) void k_csr(const int* __restrict__ rho,
                                             int* __restrict__ offs,
                                             ushort_t* __restrict__ plist) {
    __shared__ int hist[4][R_BINS];    // per-wave sub-histograms (less contention)
    __shared__ int tot[R_BINS];
    __shared__ int offl[R_BINS + 1];
    __shared__ int cur[4][R_BINS];
    int a = blockIdx.x, t = threadIdx.x, wv = t >> 6;
    for (int i = t; i < 4 * R_BINS; i += 256) ((int*)hist)[i] = 0;
    __syncthreads();
    const int* rA = rho + (size_t)a * HW;
#pragma unroll 4
    for (int i = 0; i < 64; ++i) {
        int r = rA[t + i * 256];
        atomicAdd(&hist[wv][r], 1);
    }
    __syncthreads();
    if (t < R_BINS) tot[t] = hist[0][t] + hist[1][t] + hist[2][t] + hist[3][t];
    __syncthreads();
    if (t == 0) {
        int s = 0;
        for (int r = 0; r < R_BINS; ++r) { offl[r] = s; s += tot[r]; }
        offl[R_BINS] = s;
    }
    __syncthreads();
    if (t < R_BINS) {
        int b = offl[t];
        cur[0][t] = b; b += hist[0][t];
        cur[1][t] = b; b += hist[1][t];
        cur[2][t] = b; b += hist[2][t];
        cur[3][t] = b;
    }
    if (t <= R_BINS) offs[a * (R_BINS + 1) + t] = offl[t];
    __syncthreads();
#pragma unroll 4
    for (int i = 0; i < 64; ++i) {
        int p = t + i * 256;
        int r = rA[p];
        int pos = atomicAdd(&cur[wv][r], 1);
        plist[(size_t)a * HW + pos] = (ushort_t)p;
    }
}

// ---------------- DHT as gather over CSR lists: no atomics, no shfl ----------------
__global__ __launch_bounds__(256) void k_dht_gather(const ushort_t* __restrict__ xT,
                                                    const int* __restrict__ offs,
                                                    const ushort_t* __restrict__ plist,
                                                    ushort_t* __restrict__ ht0) {
    int a = blockIdx.x, n = blockIdx.y, half = blockIdx.z;
    int t = threadIdx.x, lane = t & 63, wv = t >> 6;
    int wslot = half * 4 + wv;               // 0..7, each wave owns r = wslot mod 8
    const ushort_t* xn = xT + n * 64 + lane;
    const ushort_t* pl = plist + (size_t)a * HW;
    const int* offA = offs + a * (R_BINS + 1);
    size_t obase = (size_t)(n * AP + a + 4) * (R_BINS * CCH);
    for (int r = wslot; r < R_BINS; r += 8) {
        int off = offA[r], end = offA[r + 1];
        float acc = 0.f;
        int j = off;
        for (; j + 8 <= end; j += 8) {
            int p0 = pl[j + 0]; int p1 = pl[j + 1];
            int p2 = pl[j + 2]; int p3 = pl[j + 3];
            int p4 = pl[j + 4]; int p5 = pl[j + 5];
            int p6 = pl[j + 6]; int p7 = pl[j + 7];
            float v0 = b2f(xn[(size_t)p0 * 256]);
            float v1 = b2f(xn[(size_t)p1 * 256]);
            float v2 = b2f(xn[(size_t)p2 * 256]);
            float v3 = b2f(xn[(size_t)p3 * 256]);
            float v4 = b2f(xn[(size_t)p4 * 256]);
            float v5 = b2f(xn[(size_t)p5 * 256]);
            float v6 = b2f(xn[(size_t)p6 * 256]);
            float v7 = b2f(xn[(size_t)p7 * 256]);
            acc += ((v0 + v1) + (v2 + v3)) + ((v4 + v5) + (v6 + v7));
        }
        for (; j < end; ++j) acc += b2f(xn[(size_t)pl[j] * 256]);
        ht0[obase + r * CCH + lane] = f2b(acc);
    }
}

// ---------------- depthwise (9,1) conv + bias + relu ----------------
__global__ __launch_bounds__(256) void k_conv1(const ushort_t* __restrict__ ht0,
                                               const float* __restrict__ w1,
                                               const float* __restrict__ b1,
                                               ushort_t* __restrict__ bufA) {
    int t = threadIdx.x, c = t & 63, rr = t >> 6;
    int r = blockIdx.x * 4 + rr;
    int a = blockIdx.y, n = blockIdx.z;
    if (r >= R_BINS) return;
    float acc = b1[c];
    size_t base = ((size_t)(n * AP + a) * R_BINS + r) * CCH + c;
#pragma unroll
    for (int k = 0; k < 9; ++k)
        acc += b2f(ht0[base + (size_t)k * (R_BINS * CCH)]) * w1[c * 9 + k];
    acc = fmaxf(acc, 0.f);
    bufA[((size_t)(n * AP + a + 4) * R_BINS + r) * CCH + c] = f2b(acc);
}

// ---------------- dense (9,1) conv as MFMA GEMM: M=32760, N=64, K=576 ----------------
__global__ __launch_bounds__(256) void k_gemm(const ushort_t* __restrict__ in,
                                              const ushort_t* __restrict__ wb,
                                              const float* __restrict__ bias,
                                              ushort_t* __restrict__ out,
                                              int outOff, int outStrideN) {
    int t = threadIdx.x, lane = t & 63, wv = t >> 6;
    int m = lane & 15, q = lane >> 4;
    int n = blockIdx.y;
    int rowBase = blockIdx.x * 64 + wv * 16;
    int row = rowBase + m;
    int rowc = row < MROWS ? row : (MROWS - 1);
    const ushort_t* inN = in + (size_t)n * MPROWS * CCH;
    float4v acc[4];
#pragma unroll
    for (int i = 0; i < 4; ++i) acc[i] = (float4v){0.f, 0.f, 0.f, 0.f};

#pragma unroll
    for (int k = 0; k < 9; ++k) {
#pragma unroll
        for (int h = 0; h < 2; ++h) {
            short8 af = *(const short8*)(inN + (size_t)(rowc + k * R_BINS) * CCH + h * 32 + q * 8);
            const ushort_t* wbb = wb + (size_t)((k * 2 + h) * 4) * 512 + lane * 8;
            short8 b0 = *(const short8*)(wbb);
            short8 b1v = *(const short8*)(wbb + 512);
            short8 b2v = *(const short8*)(wbb + 1024);
            short8 b3v = *(const short8*)(wbb + 1536);
            acc[0] = __builtin_amdgcn_mfma_f32_16x16x32_bf16(af, b0, acc[0], 0, 0, 0);
            acc[1] = __builtin_amdgcn_mfma_f32_16x16x32_bf16(af, b1v, acc[1], 0, 0, 0);
            acc[2] = __builtin_amdgcn_mfma_f32_16x16x32_bf16(af, b2v, acc[2], 0, 0, 0);
            acc[3] = __builtin_amdgcn_mfma_f32_16x16x32_bf16(af, b3v, acc[3], 0, 0, 0);
        }
    }

    ushort_t* outN = out + (size_t)n * outStrideN + outOff;
#pragma unroll
    for (int cot = 0; cot < 4; ++cot) {
        int co = cot * 16 + m;
        float bv = bias[co];
#pragma unroll
        for (int i = 0; i < 4; ++i) {
            int rowD = rowBase + q * 4 + i;
            float v = fmaxf(acc[cot][i] + bv, 0.f);
            if (rowD < MROWS) outN[(size_t)rowD * CCH + co] = f2b(v);
        }
    }
}

// ---------------- inverse DHT: gather with uniform rho loads (no shfl) ----------------
__global__ __launch_bounds__(256) void k_idht(const ushort_t* __restrict__ buf3,
                                              const int* __restrict__ rho,
                                              float* __restrict__ outp) {
    __shared__ float tile[64][65];
    int t = threadIdx.x, lane = t & 63, wv = t >> 6;
    int n = blockIdx.y;
    int P0 = blockIdx.x * 64;
    int pw = P0 + wv * 16;
    float acc[16];
#pragma unroll
    for (int i = 0; i < 16; ++i) acc[i] = 0.f;
    const ushort_t* bn = buf3 + (size_t)n * A_BINS * R_BINS * CCH + lane;
    for (int a = 0; a < A_BINS; ++a) {
        const int* rA = rho + (size_t)a * HW + pw;     // wave-uniform, 16B-aligned
        int4 rv0 = *(const int4*)(rA);
        int4 rv1 = *(const int4*)(rA + 4);
        int4 rv2 = *(const int4*)(rA + 8);
        int4 rv3 = *(const int4*)(rA + 12);
        const ushort_t* ba = bn + (size_t)a * R_BINS * CCH;
        int rr[16] = {rv0.x, rv0.y, rv0.z, rv0.w, rv1.x, rv1.y, rv1.z, rv1.w,
                      rv2.x, rv2.y, rv2.z, rv2.w, rv3.x, rv3.y, rv3.z, rv3.w};
#pragma unroll
        for (int i = 0; i < 16; ++i)
            acc[i] += b2f(ba[rr[i] * CCH]);
    }
#pragma unroll
    for (int i = 0; i < 16; ++i) tile[wv * 16 + i][lane] = acc[i];
    __syncthreads();
    float* on = outp + (size_t)n * CCH * HW;
#pragma unroll
    for (int i = 0; i < 16; ++i) {
        int c = wv + i * 4;
        on[(size_t)c * HW + P0 + lane] = tile[lane][c];
    }
}

extern "C" void kernel_launch(void* const* d_in, const int* in_sizes, int n_in,
                              void* d_out, int out_size, void* d_ws, size_t ws_size,
                              hipStream_t stream) {
    const float* x   = (const float*)d_in[0];
    const int*   rho = (const int*)d_in[1];
    const float* w1  = (const float*)d_in[2];
    const float* b1  = (const float*)d_in[3];
    const float* w2  = (const float*)d_in[4];
    const float* b2  = (const float*)d_in[5];
    const float* w3  = (const float*)d_in[6];
    const float* b3  = (const float*)d_in[7];
    float* outp = (float*)d_out;

    char* ws = (char*)d_ws;
    size_t off = 0;
    auto alloc = [&](size_t bytes) -> void* {
        void* p = ws + off;
        off = (off + bytes + 255) & ~(size_t)255;
        return p;
    };
    ushort_t* xT    = (ushort_t*)alloc((size_t)HW * 256 * 2);            // 8 MB
    ushort_t* ht0   = (ushort_t*)alloc((size_t)NB * MPROWS * CCH * 2);   // 17.5 MB
    ushort_t* bufA  = (ushort_t*)alloc((size_t)NB * MPROWS * CCH * 2);   // 17.5 MB
    ushort_t* bufB  = (ushort_t*)alloc((size_t)NB * MPROWS * CCH * 2);   // 17.5 MB
    ushort_t* buf3  = (ushort_t*)alloc((size_t)NB * MROWS * CCH * 2);    // 16.8 MB
    ushort_t* w2b   = (ushort_t*)alloc(36864 * 2);
    ushort_t* w3b   = (ushort_t*)alloc(36864 * 2);
    int*      offs  = (int*)alloc((size_t)A_BINS * (R_BINS + 1) * 4);    // 132 KB
    ushort_t* plist = (ushort_t*)alloc((size_t)A_BINS * HW * 2);         // 5.9 MB

    k_transpose<<<dim3(256, 4), 256, 0, stream>>>(x, xT);
    k_zero_pads<<<96, 256, 0, stream>>>(ht0, bufA, bufB);
    k_repack<<<dim3(144, 2), 256, 0, stream>>>(w2, w3, w2b, w3b);
    k_csr<<<A_BINS, 256, 0, stream>>>(rho, offs, plist);
    k_dht_gather<<<dim3(A_BINS, NB, 2), 256, 0, stream>>>(xT, offs, plist, ht0);
    k_conv1<<<dim3(46, A_BINS, NB), 256, 0, stream>>>(ht0, w1, b1, bufA);
    k_gemm<<<dim3(512, NB), 256, 0, stream>>>(bufA, w2b, b2, bufB, 728 * CCH, MPROWS * CCH);
    k_gemm<<<dim3(512, NB), 256, 0, stream>>>(bufB, w3b, b3, buf3, 0, MROWS * CCH);
    k_idht<<<dim3(256, NB), 256, 0, stream>>>(buf3, rho, outp);
}